// Round 7
// baseline (215.375 us; speedup 1.0000x reference)
//
#include <hip/hip_runtime.h>
#include <cstdint>
#include <cstddef>

#define N_TOT   53248
#define N_HOPS  4096
#define HOP_LEN 12
#define NHEAD   8
#define FFD     1024
#define GLD     384     // gbuf leading dim: 256 (g_out) + 8 a_s + 8 a_d + pad

typedef __bf16 bf16x8 __attribute__((ext_vector_type(8)));
typedef float f32x4 __attribute__((ext_vector_type(4)));
typedef float f32x16 __attribute__((ext_vector_type(16)));

__device__ __forceinline__ unsigned short f2bf(float f) {
    unsigned int u = __float_as_uint(f);
    u += 0x7FFFu + ((u >> 16) & 1u);
    return (unsigned short)(u >> 16);
}
__device__ __forceinline__ float bf2f(unsigned short b) {
    return __uint_as_float((unsigned int)b << 16);
}
__device__ __forceinline__ void gload16(const void* g, void* l) {
    __builtin_amdgcn_global_load_lds(
        (const __attribute__((address_space(1))) void*)g,
        (__attribute__((address_space(3))) void*)l, 16, 0, 0);
}

// ---------------------------------------------------------------------------
// prep: BcT rows 0-255 = Wm^T (bf16), rows 256-263 = wsrc^T, 264-271 = wdst^T
// ---------------------------------------------------------------------------
__global__ __launch_bounds__(256) void prep_w(
    const float* __restrict__ W, const float* __restrict__ att_s,
    const float* __restrict__ att_d, unsigned short* __restrict__ BcT)
{
    int d = blockIdx.x, c = threadIdx.x;
    int wave = c >> 6;
    __shared__ float ps4[4], pd4[4];
    float wm = 0.f;
    for (int h = 0; h < NHEAD; ++h) {
        float w = W[d * 2048 + h * 256 + c];
        wm += w;
        float ps = w * att_s[h * 256 + c];
        float pd = w * att_d[h * 256 + c];
        for (int o = 32; o > 0; o >>= 1) {
            ps += __shfl_xor(ps, o);
            pd += __shfl_xor(pd, o);
        }
        if ((c & 63) == 0) { ps4[wave] = ps; pd4[wave] = pd; }
        __syncthreads();
        if (c == 0) BcT[(256 + h) * 256 + d] = f2bf(ps4[0] + ps4[1] + ps4[2] + ps4[3]);
        if (c == 1) BcT[(264 + h) * 256 + d] = f2bf(pd4[0] + pd4[1] + pd4[2] + pd4[3]);
        __syncthreads();
    }
    BcT[c * 256 + d] = f2bf(wm * 0.125f);
}

// ---------------------------------------------------------------------------
__global__ __launch_bounds__(256) void tconv(
    const float* __restrict__ in, unsigned short* __restrict__ out,
    int IS, int OS, int in_zoff, int out_zoff)
{
    __shared__ float t[32][33];
    in  += (size_t)blockIdx.z * in_zoff;
    out += (size_t)blockIdx.z * out_zoff;
    int tx = threadIdx.x, ty = threadIdx.y;
    int c0 = blockIdx.x * 32, r0 = blockIdx.y * 32;
    #pragma unroll
    for (int k = 0; k < 4; ++k)
        t[ty + 8 * k][tx] = in[(size_t)(r0 + ty + 8 * k) * IS + c0 + tx];
    __syncthreads();
    #pragma unroll
    for (int k = 0; k < 4; ++k)
        out[(size_t)(c0 + ty + 8 * k) * OS + r0 + tx] = f2bf(t[tx][ty + 8 * k]);
}

// ---------------------------------------------------------------------------
__global__ __launch_bounds__(256) void cvt_bf16(
    const float* __restrict__ in, unsigned short* __restrict__ out, int n4)
{
    int i = blockIdx.x * 256 + threadIdx.x;
    if (i >= n4) return;
    float4 v = ((const float4*)in)[i];
    ushort4 o;
    o.x = f2bf(v.x); o.y = f2bf(v.y); o.z = f2bf(v.z); o.w = f2bf(v.w);
    ((ushort4*)out)[i] = o;
}

// ---------------------------------------------------------------------------
// hop softmax + weighted x aggregation (logits from bf16 gbuf cols 256..271)
// ---------------------------------------------------------------------------
__global__ __launch_bounds__(256) void hop_z(
    const unsigned short* __restrict__ xb, const unsigned short* __restrict__ gb,
    unsigned short* __restrict__ z)
{
    int j = blockIdx.x, tid = threadIdx.x;
    __shared__ float xr[13][256];
    __shared__ float sm[NHEAD][13];
    __shared__ float walpha[NHEAD][13];
    __shared__ float mxs[NHEAD], invs[NHEAD];

    for (int i = tid; i < 13 * 32; i += 256) {
        int r = i >> 5, c8 = (i & 31) * 8;
        int src = (r == 0) ? j : (N_HOPS + j * HOP_LEN + r - 1);
        uint4 u = *(const uint4*)&xb[(size_t)src * 256 + c8];
        float4 lo, hi;
        lo.x = bf2f((unsigned short)(u.x & 0xFFFF)); lo.y = bf2f((unsigned short)(u.x >> 16));
        lo.z = bf2f((unsigned short)(u.y & 0xFFFF)); lo.w = bf2f((unsigned short)(u.y >> 16));
        hi.x = bf2f((unsigned short)(u.z & 0xFFFF)); hi.y = bf2f((unsigned short)(u.z >> 16));
        hi.z = bf2f((unsigned short)(u.w & 0xFFFF)); hi.w = bf2f((unsigned short)(u.w >> 16));
        *(float4*)&xr[r][c8] = lo;
        *(float4*)&xr[r][c8 + 4] = hi;
    }
    if (tid < NHEAD * 13) {
        int h = tid / 13, k = tid % 13;
        int src = (k == 0) ? j : (N_HOPS + j * HOP_LEN + k - 1);
        float ad = bf2f(gb[(size_t)j * GLD + 264 + h]);
        float v = bf2f(gb[(size_t)src * GLD + 256 + h]) + ad;
        sm[h][k] = v > 0.f ? v : 0.2f * v;
    }
    __syncthreads();
    if (tid < NHEAD) {
        int h = tid;
        float mx = sm[h][0];
        for (int k = 1; k < 13; ++k) mx = fmaxf(mx, sm[h][k]);
        float sum = 2.f * expf(sm[h][0] - mx);   // self edge counted twice
        for (int k = 1; k < 13; ++k) sum += expf(sm[h][k] - mx);
        mxs[h] = mx;
        invs[h] = 0.125f / (sum + 1e-16f);
    }
    __syncthreads();
    if (tid < NHEAD * 13) {
        int h = tid / 13, k = tid % 13;
        walpha[h][k] = (k == 0 ? 2.f : 1.f) * expf(sm[h][k] - mxs[h]) * invs[h];
    }
    __syncthreads();
    for (int h = 0; h < NHEAD; ++h) {
        float acc = 0.f;
        #pragma unroll
        for (int r = 0; r < 13; ++r) acc += walpha[h][r] * xr[r][tid];
        z[((size_t)j * NHEAD + h) * 256 + tid] = f2bf(acc);
    }
}

// ---------------------------------------------------------------------------
// bf16 MFMA GEMM (m97 structure): C[M,Nc](ldc) = A @ BT^T + bias
// ---------------------------------------------------------------------------
template <int RELU, int OUT_BF16>
__global__ __launch_bounds__(256) void gemm_bt(
    const unsigned short* __restrict__ A, const unsigned short* __restrict__ BT,
    const float* __restrict__ bias, void* __restrict__ Cout,
    int M, int Nc, int K, int ldc)
{
    __shared__ __align__(16) unsigned short As[128 * 32];
    __shared__ __align__(16) unsigned short Bs[128 * 32];
    const int tid = threadIdx.x;
    const int l = tid & 63;
    const int bm = blockIdx.y * 128, bn = blockIdx.x * 128;
    const int wm = ((tid >> 6) >> 1) * 64, wn = ((tid >> 6) & 1) * 64;

    const int r0 = tid >> 2, ke0 = (tid & 3) * 8;
    const int r1 = (256 + tid) >> 2, ke1 = ((256 + tid) & 3) * 8;
    const unsigned short* ga0 = A + (size_t)(bm + r0) * K + ke0;
    const unsigned short* ga1 = A + (size_t)(bm + r1) * K + ke1;
    const unsigned short* gb0 = BT + (size_t)(bn + r0) * K + ke0;
    const unsigned short* gb1 = BT + (size_t)(bn + r1) * K + ke1;

    f32x4 acc[4][4];
    #pragma unroll
    for (int m = 0; m < 4; ++m)
        #pragma unroll
        for (int n = 0; n < 4; ++n)
            acc[m][n] = (f32x4){0.f, 0.f, 0.f, 0.f};

    const int lrow = l & 15, lk8 = (l >> 4) * 8;

    for (int k0 = 0; k0 < K; k0 += 32) {
        gload16(ga0 + k0, &As[(size_t)tid * 8]);
        gload16(ga1 + k0, &As[(size_t)(256 + tid) * 8]);
        gload16(gb0 + k0, &Bs[(size_t)tid * 8]);
        gload16(gb1 + k0, &Bs[(size_t)(256 + tid) * 8]);
        __syncthreads();
        bf16x8 af[4], bfr[4];
        #pragma unroll
        for (int m = 0; m < 4; ++m)
            af[m] = *(const bf16x8*)&As[(wm + m * 16 + lrow) * 32 + lk8];
        #pragma unroll
        for (int n = 0; n < 4; ++n)
            bfr[n] = *(const bf16x8*)&Bs[(wn + n * 16 + lrow) * 32 + lk8];
        #pragma unroll
        for (int m = 0; m < 4; ++m)
            #pragma unroll
            for (int n = 0; n < 4; ++n)
                acc[m][n] = __builtin_amdgcn_mfma_f32_16x16x32_bf16(
                    af[m], bfr[n], acc[m][n], 0, 0, 0);
        __syncthreads();
    }

    const int orow = (l >> 4) * 4, ocol = l & 15;
    #pragma unroll
    for (int m = 0; m < 4; ++m) {
        int gr = bm + wm + m * 16 + orow;
        #pragma unroll
        for (int n = 0; n < 4; ++n) {
            int gc = bn + wn + n * 16 + ocol;
            float bv = bias[gc];
            #pragma unroll
            for (int r = 0; r < 4; ++r) {
                float v = acc[m][n][r] + bv;
                if (RELU) v = fmaxf(v, 0.f);
                if (OUT_BF16)
                    ((unsigned short*)Cout)[(size_t)(gr + r) * ldc + gc] = f2bf(v);
                else
                    ((float*)Cout)[(size_t)(gr + r) * ldc + gc] = v;
            }
        }
    }
}

// ---------------------------------------------------------------------------
// split-K: partial[z][M][Nc] (bf16) = A[:, z*Ksl:(z+1)*Ksl] @ BT^T
// ---------------------------------------------------------------------------
__global__ __launch_bounds__(256) void gemm_bt_sk(
    const unsigned short* __restrict__ A, const unsigned short* __restrict__ BT,
    unsigned short* __restrict__ Cpart, int M, int Nc, int Ksl, int ldA)
{
    __shared__ __align__(16) unsigned short As[128 * 32];
    __shared__ __align__(16) unsigned short Bs[128 * 32];
    const int tid = threadIdx.x;
    const int l = tid & 63;
    const int bm = blockIdx.y * 128, bn = blockIdx.x * 128;
    const int koff = blockIdx.z * Ksl;
    const int wm = ((tid >> 6) >> 1) * 64, wn = ((tid >> 6) & 1) * 64;

    const int r0 = tid >> 2, ke0 = (tid & 3) * 8;
    const int r1 = (256 + tid) >> 2, ke1 = ((256 + tid) & 3) * 8;
    const unsigned short* ga0 = A + (size_t)(bm + r0) * ldA + koff + ke0;
    const unsigned short* ga1 = A + (size_t)(bm + r1) * ldA + koff + ke1;
    const unsigned short* gb0 = BT + (size_t)(bn + r0) * ldA + koff + ke0;
    const unsigned short* gb1 = BT + (size_t)(bn + r1) * ldA + koff + ke1;

    f32x4 acc[4][4];
    #pragma unroll
    for (int m = 0; m < 4; ++m)
        #pragma unroll
        for (int n = 0; n < 4; ++n)
            acc[m][n] = (f32x4){0.f, 0.f, 0.f, 0.f};

    const int lrow = l & 15, lk8 = (l >> 4) * 8;

    for (int k0 = 0; k0 < Ksl; k0 += 32) {
        gload16(ga0 + k0, &As[(size_t)tid * 8]);
        gload16(ga1 + k0, &As[(size_t)(256 + tid) * 8]);
        gload16(gb0 + k0, &Bs[(size_t)tid * 8]);
        gload16(gb1 + k0, &Bs[(size_t)(256 + tid) * 8]);
        __syncthreads();
        bf16x8 af[4], bfr[4];
        #pragma unroll
        for (int m = 0; m < 4; ++m)
            af[m] = *(const bf16x8*)&As[(wm + m * 16 + lrow) * 32 + lk8];
        #pragma unroll
        for (int n = 0; n < 4; ++n)
            bfr[n] = *(const bf16x8*)&Bs[(wn + n * 16 + lrow) * 32 + lk8];
        #pragma unroll
        for (int m = 0; m < 4; ++m)
            #pragma unroll
            for (int n = 0; n < 4; ++n)
                acc[m][n] = __builtin_amdgcn_mfma_f32_16x16x32_bf16(
                    af[m], bfr[n], acc[m][n], 0, 0, 0);
        __syncthreads();
    }

    unsigned short* Cp = Cpart + (size_t)blockIdx.z * M * Nc;
    const int orow = (l >> 4) * 4, ocol = l & 15;
    #pragma unroll
    for (int m = 0; m < 4; ++m) {
        int gr = bm + wm + m * 16 + orow;
        #pragma unroll
        for (int n = 0; n < 4; ++n) {
            int gc = bn + wn + n * 16 + ocol;
            #pragma unroll
            for (int r = 0; r < 4; ++r)
                Cp[(size_t)(gr + r) * Nc + gc] = f2bf(acc[m][n][r]);
        }
    }
}

// ---------------------------------------------------------------------------
// hop reduce: gbuf[row][col] = bf16( sum_z hopP[z][row][col] + bias[col] )
// ---------------------------------------------------------------------------
__global__ __launch_bounds__(256) void red_hop(
    const unsigned short* __restrict__ P, const float* __restrict__ bias,
    unsigned short* __restrict__ gbuf)
{
    int i = blockIdx.x * 256 + threadIdx.x;       // group of 4 cols
    int row = i >> 6, c4 = (i & 63) * 4;
    float4 s = { 0.f, 0.f, 0.f, 0.f };
    #pragma unroll
    for (int zz = 0; zz < 8; ++zz) {
        ushort4 u = *(const ushort4*)&P[(size_t)zz * N_HOPS * 256 + (size_t)row * 256 + c4];
        s.x += bf2f(u.x); s.y += bf2f(u.y); s.z += bf2f(u.z); s.w += bf2f(u.w);
    }
    float4 bv = *(const float4*)&bias[c4];
    ushort4 o;
    o.x = f2bf(s.x + bv.x); o.y = f2bf(s.y + bv.y);
    o.z = f2bf(s.z + bv.z); o.w = f2bf(s.w + bv.w);
    *(ushort4*)&gbuf[(size_t)row * GLD + c4] = o;
}

// ---------------------------------------------------------------------------
// x1 = LayerNorm(a + b) -> bf16; a bf16 stride GLD, b bf16 stride 256
// ---------------------------------------------------------------------------
__global__ __launch_bounds__(256) void ln_add_bb(
    const unsigned short* __restrict__ a, const unsigned short* __restrict__ b,
    const float* __restrict__ g, const float* __restrict__ be,
    unsigned short* __restrict__ outp)
{
    int wave = threadIdx.x >> 6, lane = threadIdx.x & 63;
    int n = blockIdx.x * 4 + wave;
    ushort4 av = *(const ushort4*)&a[(size_t)n * GLD + lane * 4];
    ushort4 bv = ((const ushort4*)b)[(size_t)n * 64 + lane];
    float v[4];
    v[0] = bf2f(av.x) + bf2f(bv.x); v[1] = bf2f(av.y) + bf2f(bv.y);
    v[2] = bf2f(av.z) + bf2f(bv.z); v[3] = bf2f(av.w) + bf2f(bv.w);
    float s = v[0] + v[1] + v[2] + v[3];
    for (int o = 32; o > 0; o >>= 1) s += __shfl_xor(s, o);
    float mu = s * (1.f / 256.f);
    float q = 0.f;
    #pragma unroll
    for (int i = 0; i < 4; ++i) { float d = v[i] - mu; q += d * d; }
    for (int o = 32; o > 0; o >>= 1) q += __shfl_xor(q, o);
    float rstd = rsqrtf(q * (1.f / 256.f) + 1e-5f);
    int c = lane * 4;
    float4 gv = *(const float4*)&g[c];
    float4 bev = *(const float4*)&be[c];
    ushort4 o4;
    o4.x = f2bf((v[0] - mu) * rstd * gv.x + bev.x);
    o4.y = f2bf((v[1] - mu) * rstd * gv.y + bev.y);
    o4.z = f2bf((v[2] - mu) * rstd * gv.z + bev.z);
    o4.w = f2bf((v[3] - mu) * rstd * gv.w + bev.w);
    ((ushort4*)outp)[(size_t)n * 64 + lane] = o4;
}

// ---------------------------------------------------------------------------
// fused FFN + LN2 v3: out = LN( relu(x1@W1+b1)@W2 + b2 + x1 )
// 256 thr / 4 waves / 64-row block, 32x32x16 MFMA, x1 in regs.
// Stage1 SWAPPED (mfma(W1,x1) -> C[hc][row]): packed b64 sH writes.
// Deep register pipelining: wf[8] fragment groups (static idx) so the
// compiler issues 8 ds_reads back-to-back instead of read->wait->mfma.
// LDS: sW1 32K | sW2 32K | sH 8K | sB1 4K = 76K -> 2 blocks/CU.
// ---------------------------------------------------------------------------
__global__ __launch_bounds__(256, 2) void fused_ffn(
    const unsigned short* __restrict__ x1b, const unsigned short* __restrict__ W1T,
    const float* __restrict__ b1, const unsigned short* __restrict__ W2T,
    const float* __restrict__ b2, const float* __restrict__ g2,
    const float* __restrict__ be2, float* __restrict__ out)
{
    __shared__ __align__(16) char smem[77824];
    unsigned short* sW1u = (unsigned short*)smem;            // [64 hc][256k] swz
    unsigned short* sW2u = (unsigned short*)(smem + 32768);  // [256 fc][64k] swz
    unsigned short* sHu  = (unsigned short*)(smem + 65536);  // [64 r][64hc] swz
    float*          sB1  = (float*)(smem + 73728);           // [1024]

    const int tid = threadIdx.x, l = tid & 63, w = tid >> 6;
    const int l31 = l & 31, h1 = l >> 5;
    const int row0 = blockIdx.x * 64;
    const int arow = (w & 1) * 32 + l31;      // x1 row this lane owns (stage1 B)
    const int hcl  = (w >> 1) * 32 + l31;     // W1 hcol this lane owns (stage1 A)
    const int hx   = hcl & 7;

    // ---- prologue: stage chunk-0 W1/W2 (pre-swizzled source), b1 -> LDS
    #pragma unroll
    for (int i = 0; i < 8; ++i) {
        int c = i * 256 + tid;
        int r = c >> 5, s = c & 31;
        gload16(W1T + (size_t)r * 256 + ((s ^ (r & 7)) * 8), sW1u + c * 8);
    }
    #pragma unroll
    for (int i = 0; i < 8; ++i) {
        int c = i * 256 + tid;
        int r = c >> 3, s = c & 7;
        gload16(W2T + (size_t)r * 1024 + ((s ^ (r & 7)) * 8), sW2u + c * 8);
    }
    {
        float4 bv = ((const float4*)b1)[tid];
        *(float4*)&sB1[tid * 4] = bv;
    }
    // x1 rows -> registers (B-fragments: col=lane&31=row, k = ks*16 + h1*8 + j)
    bf16x8 a[16];
    {
        const unsigned short* xr = x1b + (size_t)(row0 + arow) * 256 + h1 * 8;
        #pragma unroll
        for (int ks = 0; ks < 16; ++ks)
            a[ks] = *(const bf16x8*)(xr + ks * 16);
    }
    f32x16 facc[2][2];
    #pragma unroll
    for (int m = 0; m < 2; ++m)
        #pragma unroll
        for (int n = 0; n < 2; ++n)
            facc[m][n] = (f32x16)(0.f);
    __syncthreads();   // W(0), b1 landed & visible

    for (int ch = 0; ch < 16; ++ch) {
        // ---- stage1 (swapped): hacc = W1chunk(32hc) x x1(32rows), K=256
        f32x16 hA = (f32x16)(0.f);
        {
            bf16x8 wf[8];
            #pragma unroll
            for (int ks = 0; ks < 8; ++ks)
                wf[ks] = *(const bf16x8*)&sW1u[hcl * 256 + (((2 * ks + h1) ^ hx) * 8)];
            #pragma unroll
            for (int ks = 0; ks < 8; ++ks)
                hA = __builtin_amdgcn_mfma_f32_32x32x16_bf16(wf[ks], a[ks], hA, 0, 0, 0);
            #pragma unroll
            for (int ks = 0; ks < 8; ++ks)
                wf[ks] = *(const bf16x8*)&sW1u[hcl * 256 + (((2 * (ks + 8) + h1) ^ hx) * 8)];
            #pragma unroll
            for (int ks = 0; ks < 8; ++ks)
                hA = __builtin_amdgcn_mfma_f32_32x32x16_bf16(wf[ks], a[ks + 8], hA, 0, 0, 0);
        }
        // pack 4 consecutive hcols per b64 write: C[hc][row], hc from reg
        #pragma unroll
        for (int g = 0; g < 4; ++g) {
            int hcb = (w >> 1) * 32 + 8 * g + 4 * h1;          // hc base (chunk-local)
            float4 bv = *(const float4*)&sB1[ch * 64 + hcb];
            ushort4 o;
            o.x = f2bf(fmaxf(hA[4 * g + 0] + bv.x, 0.f));
            o.y = f2bf(fmaxf(hA[4 * g + 1] + bv.y, 0.f));
            o.z = f2bf(fmaxf(hA[4 * g + 2] + bv.z, 0.f));
            o.w = f2bf(fmaxf(hA[4 * g + 3] + bv.w, 0.f));
            int slot = ((w >> 1) * 4 + g) ^ (arow & 7);
            *(ushort4*)&sHu[arow * 64 + slot * 8 + h1 * 4] = o;
        }
        __syncthreads();                       // alpha: sH visible, sW1 free
        if (ch < 15) {
            #pragma unroll
            for (int i = 0; i < 8; ++i) {
                int c = i * 256 + tid;
                int r = c >> 5, s = c & 31;
                gload16(W1T + (size_t)((ch + 1) * 64 + r) * 256 + ((s ^ (r & 7)) * 8),
                        sW1u + c * 8);
            }
        }
        // ---- stage2: facc += h @ W2chunk ; wave: 64 rows x 64 fcols
        #pragma unroll
        for (int kp = 0; kp < 2; ++kp) {
            bf16x8 am[2][2], bn[2][2];
            #pragma unroll
            for (int q = 0; q < 2; ++q) {
                int ks = kp * 2 + q;
                #pragma unroll
                for (int m = 0; m < 2; ++m) {
                    int r = m * 32 + l31;
                    am[q][m] = *(const bf16x8*)&sHu[r * 64 + (((2 * ks + h1) ^ (r & 7)) * 8)];
                }
                #pragma unroll
                for (int n = 0; n < 2; ++n) {
                    int fc = w * 64 + n * 32 + l31;
                    bn[q][n] = *(const bf16x8*)&sW2u[fc * 64 + (((2 * ks + h1) ^ (fc & 7)) * 8)];
                }
            }
            #pragma unroll
            for (int q = 0; q < 2; ++q)
                #pragma unroll
                for (int m = 0; m < 2; ++m)
                    #pragma unroll
                    for (int n = 0; n < 2; ++n)
                        facc[m][n] = __builtin_amdgcn_mfma_f32_32x32x16_bf16(
                            am[q][m], bn[q][n], facc[m][n], 0, 0, 0);
        }
        __syncthreads();                       // beta: sW2 free, sH free
        if (ch < 15) {
            #pragma unroll
            for (int i = 0; i < 8; ++i) {
                int c = i * 256 + tid;
                int r = c >> 3, s = c & 7;
                gload16(W2T + (size_t)r * 1024 + (ch + 1) * 64 + ((s ^ (r & 7)) * 8),
                        sW2u + c * 8);
            }
        }
    }

    // ---- epilogue: residual + b2, LN2, fp32 out
    float b2c[2], g2c[2], be2c[2];
    #pragma unroll
    for (int n = 0; n < 2; ++n) {
        int fc = w * 64 + n * 32 + l31;
        b2c[n] = b2[fc]; g2c[n] = g2[fc]; be2c[n] = be2[fc];
    }
    // share x1 regs via dead sW1 region: [64 rows][256 k], slot-XOR
    if (w < 2) {
        #pragma unroll
        for (int ks = 0; ks < 16; ++ks)
            *(bf16x8*)&sW1u[arow * 256 + (((2 * ks + h1) ^ (arow & 7)) * 8)] = a[ks];
    }
    __syncthreads();
    #pragma unroll
    for (int m = 0; m < 2; ++m)
        #pragma unroll
        for (int n = 0; n < 2; ++n)
            #pragma unroll
            for (int reg = 0; reg < 16; ++reg) {
                int r2 = m * 32 + (reg & 3) + 8 * (reg >> 2) + 4 * h1;
                int fc = w * 64 + n * 32 + l31;
                float res = bf2f(sW1u[r2 * 256 + ((((fc >> 3) ^ (r2 & 7)) * 8) | (fc & 7))]);
                facc[m][n][reg] += b2c[n] + res;
            }
    // LN stats: per-(m,reg) reduce over 32 fcol-lanes, cross-wave via LDS
    float* lnS = (float*)sW2u;          // [64][4]
    float* lnQ = lnS + 256;             // [64][4]
    float* lnM = lnQ + 256;             // [64]
    float* lnR = lnM + 64;              // [64]
    #pragma unroll
    for (int m = 0; m < 2; ++m)
        #pragma unroll
        for (int reg = 0; reg < 16; ++reg) {
            float s = facc[m][0][reg] + facc[m][1][reg];
            float q = facc[m][0][reg] * facc[m][0][reg]
                    + facc[m][1][reg] * facc[m][1][reg];
            #pragma unroll
            for (int o = 16; o >= 1; o >>= 1) {
                s += __shfl_xor(s, o);
                q += __shfl_xor(q, o);
            }
            if (l31 == 0) {
                int r2 = m * 32 + (reg & 3) + 8 * (reg >> 2) + 4 * h1;
                lnS[r2 * 4 + w] = s;
                lnQ[r2 * 4 + w] = q;
            }
        }
    __syncthreads();
    if (tid < 64) {
        float s = lnS[tid * 4] + lnS[tid * 4 + 1] + lnS[tid * 4 + 2] + lnS[tid * 4 + 3];
        float q = lnQ[tid * 4] + lnQ[tid * 4 + 1] + lnQ[tid * 4 + 2] + lnQ[tid * 4 + 3];
        float mu = s * (1.f / 256.f);
        lnM[tid] = mu;
        lnR[tid] = rsqrtf(q * (1.f / 256.f) - mu * mu + 1e-5f);
    }
    __syncthreads();
    #pragma unroll
    for (int m = 0; m < 2; ++m)
        #pragma unroll
        for (int reg = 0; reg < 16; ++reg) {
            int r2 = m * 32 + (reg & 3) + 8 * (reg >> 2) + 4 * h1;
            float mu = lnM[r2], rs = lnR[r2];
            #pragma unroll
            for (int n = 0; n < 2; ++n) {
                int fc = w * 64 + n * 32 + l31;
                out[(size_t)(row0 + r2) * 256 + fc] =
                    (facc[m][n][reg] - mu) * rs * g2c[n] + be2c[n];
            }
        }
}

// ---------------------------------------------------------------------------
extern "C" void kernel_launch(void* const* d_in, const int* in_sizes, int n_in,
                              void* d_out, int out_size, void* d_ws, size_t ws_size,
                              hipStream_t stream)
{
    const float* x       = (const float*)d_in[0];
    const float* gat_W   = (const float*)d_in[2];
    const float* att_src = (const float*)d_in[3];
    const float* att_dst = (const float*)d_in[4];
    const float* gat_b   = (const float*)d_in[5];
    const float* W1      = (const float*)d_in[6];
    const float* b1      = (const float*)d_in[7];
    const float* W2      = (const float*)d_in[8];
    const float* b2      = (const float*)d_in[9];
    const float* ln1_g   = (const float*)d_in[10];
    const float* ln1_b   = (const float*)d_in[11];
    const float* ln2_g   = (const float*)d_in[12];
    const float* ln2_b   = (const float*)d_in[13];
    float* out = (float*)d_out;

    char* p = (char*)d_ws;
    auto carve = [&p](size_t bytes) { char* r = p; p += (bytes + 255) & ~(size_t)255; return r; };
    unsigned short* gbuf = (unsigned short*)carve((size_t)N_TOT * GLD * 2);  // bf16 [N][384]
    unsigned short* x1b  = (unsigned short*)carve((size_t)N_TOT * 256 * 2);  // xb -> x1
    unsigned short* z    = (unsigned short*)carve((size_t)N_HOPS * 2048 * 2);
    unsigned short* hopP = (unsigned short*)carve((size_t)8 * N_HOPS * 256 * 2);
    unsigned short* BcT  = (unsigned short*)carve((size_t)GLD * 256 * 2);
    unsigned short* B2T  = (unsigned short*)carve((size_t)2048 * 256 * 2);
    unsigned short* W1T  = (unsigned short*)carve((size_t)FFD * 256 * 2);
    unsigned short* W2T  = (unsigned short*)carve((size_t)256 * FFD * 2);
    float*          bias384 = (float*)carve(GLD * 4);

    // 0. small prep
    hipMemsetAsync(BcT + 272 * 256, 0, (size_t)(GLD - 272) * 256 * 2, stream);
    hipMemcpyAsync(bias384, gat_b, 256 * 4, hipMemcpyDeviceToDevice, stream);
    hipMemsetAsync(bias384 + 256, 0, (GLD - 256) * 4, stream);
    // 1. weight prep + transposes
    hipLaunchKernelGGL(prep_w, dim3(256), dim3(256), 0, stream,
                       gat_W, att_src, att_dst, BcT);
    hipLaunchKernelGGL(tconv, dim3(8, 8, 8), dim3(32, 8), 0, stream,
                       gat_W, B2T, 2048, 2048, 256, 256);
    hipLaunchKernelGGL(tconv, dim3(32, 8, 1), dim3(32, 8), 0, stream,
                       W1, W1T, 1024, 256, 0, 0);
    hipLaunchKernelGGL(tconv, dim3(8, 32, 1), dim3(32, 8), 0, stream,
                       W2, W2T, 256, 1024, 0, 0);
    // 2. x -> bf16
    hipLaunchKernelGGL(cvt_bf16, dim3(N_TOT * 256 / 4 / 256), dim3(256), 0, stream,
                       x, x1b, N_TOT * 256 / 4);
    // 3. combined GEMM: gbuf[n][0:256]=x@Wm+gat_b (bf16), [256:272]=attn logits
    hipLaunchKernelGGL((gemm_bt<0, 1>), dim3(GLD / 128, N_TOT / 128), dim3(256), 0, stream,
                       x1b, BcT, bias384, gbuf, N_TOT, GLD, 256, GLD);
    // 4. hop softmax + aggregation
    hipLaunchKernelGGL(hop_z, dim3(N_HOPS), dim3(256), 0, stream,
                       x1b, gbuf, z);
    // 5. g_hop = z @ B2 + bias (split-K=8 partials, then reduce)
    hipLaunchKernelGGL(gemm_bt_sk, dim3(2, N_HOPS / 128, 8), dim3(256), 0, stream,
                       z, B2T, hopP, N_HOPS, 256, 256, 2048);
    hipLaunchKernelGGL(red_hop, dim3(N_HOPS * 64 / 256), dim3(256), 0, stream,
                       hopP, gat_b, gbuf);
    // 6. x1 = LN(g + x) -> bf16 (in place over x1b)
    hipLaunchKernelGGL(ln_add_bb, dim3(N_TOT / 4), dim3(256), 0, stream,
                       gbuf, x1b, ln1_g, ln1_b, x1b);
    // 7. fused FFN1+FFN2+LN2 -> out (fp32), hid stays on-chip
    hipLaunchKernelGGL(fused_ffn, dim3(N_TOT / 64), dim3(256), 0, stream,
                       x1b, W1T, b1, W2T, b2, ln2_g, ln2_b, out);
    (void)in_sizes; (void)n_in; (void)out_size; (void)ws_size;
}